// Round 1
// 680.299 us; speedup vs baseline: 1.2526x; 1.2526x over previous
//
#include <hip/hip_runtime.h>
#include <math.h>

typedef unsigned short u16;
typedef unsigned int u32;
typedef __attribute__((ext_vector_type(8))) short short8;   // 8 bf16 (4 VGPRs)
typedef __attribute__((ext_vector_type(4))) float f32x4;

__device__ __forceinline__ float bf2f(u16 u) {
  union { u32 i; float f; } v; v.i = ((u32)u) << 16; return v.f;
}
__device__ __forceinline__ u16 f2bf(float f) {
  union { float f; u32 i; } v; v.f = f;
  u32 i = v.i;
  i += 0x7fffu + ((i >> 16) & 1u);   // round-to-nearest-even
  return (u16)(i >> 16);
}

// dtype-polymorphic loads (F32: inputs are float32; else bf16 bits)
template<bool F32>
__device__ __forceinline__ float ld(const void* p, int i) {
  if (F32) return ((const float*)p)[i];
  return bf2f(((const u16*)p)[i]);
}

// ---------------------------------------------------------------------------
// Kernel 0: detect input dtype (fp32 vs bf16-packed).
// ---------------------------------------------------------------------------
__global__ __launch_bounds__(64)
void detect_kernel(const void* __restrict__ xv, int* __restrict__ flag) {
  const u32* xw = (const u32*)xv;
  const int t = threadIdx.x;
  int bad = 0;
  for (int i = t; i < 1024; i += 64) {
    const int e = (int)((xw[i] >> 7) & 0xFF);
    if (e < 90 || e > 150) bad++;
  }
#pragma unroll
  for (int m = 1; m < 64; m <<= 1) bad += __shfl_xor(bad, m);
  if (t == 0) *flag = (bad > 256) ? 1 : 0;
}

// ---------------------------------------------------------------------------
// Kernel 1 (MFMA rewrite): LN1 + shifted-window attention + proj + residual.
// Block = 256 thr (4 waves), chunk = 8 windows = 64 tokens, 8192 chunks,
// persistent grid of 2048 blocks (weights preloaded in registers once).
//   phase 1: LN1 + shifted gather -> aL[64x72] bf16 (wave w: tokens w*16..+15)
//   phase 2: QKV MFMA 64x64 @ 64x192 (wave w: N-cols w*48..+47) -> q/k/v LDS
//   phase 3: per-(window,head) 8x8 softmax on VALU, k/v rows via ds_read_b128
//            (wave w handles window rep*4+w, rep=0,1) -> O bf16 into aL
//   phase 4: proj MFMA 64x64 @ 64x64 (wave w: N-cols w*16..+15) + scattered
//            residual epilogue (bug-faithful window-reverse mapping)
// MFMA layouts (verified, same as mlp_kernel): A m=lane&15,k=quad*8+j;
// B n=lane&15,k=quad*8+j; C/D col=lane&15,row=quad*4+r.
// ---------------------------------------------------------------------------
template<bool F32>
__device__ __forceinline__ void attn_body(
    const void* __restrict__ x,
    const void* __restrict__ n1g, const void* __restrict__ n1b,
    const void* __restrict__ qkvw, const void* __restrict__ qkvb,
    const void* __restrict__ rpb,
    const void* __restrict__ projw, const void* __restrict__ projb,
    float* __restrict__ out,
    u16* __restrict__ aL, u16* __restrict__ qL,
    u16* __restrict__ kL, u16* __restrict__ vL)
{
  const int tid  = threadIdx.x;
  const int w    = tid >> 6, l = tid & 63;
  const int quad = l >> 4,  col = l & 15;

  const float g1 = ld<F32>(n1g, l), be1 = ld<F32>(n1b, l);

  // ---- preload B-fragments into registers (once per block) ----
  short8 bq[3][2];                 // qkv cols w*48 + nt*16 + col, [nt][kt]
#pragma unroll
  for (int nt = 0; nt < 3; ++nt)
#pragma unroll
    for (int kt = 0; kt < 2; ++kt) {
      short8 f;
#pragma unroll
      for (int j = 0; j < 8; ++j) {
        const int k = kt*32 + quad*8 + j;
        f[j] = (short)f2bf(ld<F32>(qkvw, k*192 + w*48 + nt*16 + col));
      }
      bq[nt][kt] = f;
    }
  float qb[3];
#pragma unroll
  for (int nt = 0; nt < 3; ++nt) qb[nt] = ld<F32>(qkvb, w*48 + nt*16 + col);
  short8 bp[2];                    // proj cols w*16 + col, [kt]
#pragma unroll
  for (int kt = 0; kt < 2; ++kt) {
    short8 f;
#pragma unroll
    for (int j = 0; j < 8; ++j) {
      const int k = kt*32 + quad*8 + j;
      f[j] = (short)f2bf(ld<F32>(projw, k*64 + w*16 + col));
    }
    bp[kt] = f;
  }
  const float pb = ld<F32>(projb, w*16 + col);

  for (int chunk = blockIdx.x; chunk < 8192; chunk += gridDim.x) {
    const int b     = chunk >> 12;
    const int wbase = (chunk & 4095) << 3;   // first of 8 windows

    // ---- phase 1: LN1 + shifted gather (lane = channel) ----
#pragma unroll 4
    for (int t = 0; t < 16; ++t) {
      const int tok  = w*16 + t;
      const int widx = wbase + (tok >> 3);
      const int s    = tok & 7;
      const int wz = widx >> 10, wy = (widx >> 5) & 31, wx = widx & 31;
      const int od = (2*wz + ((s>>2)&1) + 1) & 63;
      const int oh = (2*wy + ((s>>1)&1) + 1) & 63;
      const int ow = (2*wx + ( s    &1) + 1) & 63;
      const float v = ld<F32>(x, (((b<<18) + ((od<<12)|(oh<<6)|ow)) << 6) + l);
      float s1 = v, sq = v * v;
#pragma unroll
      for (int m = 1; m < 64; m <<= 1) {
        s1 += __shfl_xor(s1, m);
        sq += __shfl_xor(sq, m);
      }
      const float mu  = s1 * 0.015625f;
      const float var = sq * 0.015625f - mu * mu;
      aL[tok*72 + l] = f2bf((v - mu) * rsqrtf(var + 1e-5f) * g1 + be1);
    }
    __syncthreads();

    // ---- phase 2: QKV MFMA, wave's 64x48 slab -> q/k/v LDS (bf16) ----
    f32x4 acc[4][3];
#pragma unroll
    for (int mt = 0; mt < 4; ++mt)
#pragma unroll
      for (int nt = 0; nt < 3; ++nt) acc[mt][nt] = (f32x4){0.f,0.f,0.f,0.f};
#pragma unroll
    for (int kt = 0; kt < 2; ++kt) {
      short8 aF[4];
#pragma unroll
      for (int mt = 0; mt < 4; ++mt)
        aF[mt] = *(const short8*)&aL[(mt*16 + col)*72 + kt*32 + quad*8];
#pragma unroll
      for (int mt = 0; mt < 4; ++mt)
#pragma unroll
        for (int nt = 0; nt < 3; ++nt)
          acc[mt][nt] = __builtin_amdgcn_mfma_f32_16x16x32_bf16(
              aF[mt], bq[nt][kt], acc[mt][nt], 0, 0, 0);
    }
#pragma unroll
    for (int nt = 0; nt < 3; ++nt) {
      const int nb  = w*48 + nt*16;                 // global qkv col base
      u16* dst      = (nb < 64) ? qL : (nb < 128) ? kL : vL;
      const int chb = (nb & 63) + col;
      const float scl = (nb < 64) ? 0.35355339059327373f : 1.0f;
#pragma unroll
      for (int mt = 0; mt < 4; ++mt)
#pragma unroll
        for (int r = 0; r < 4; ++r) {
          const int tokr = mt*16 + quad*4 + r;
          dst[tokr*72 + chb] = f2bf((acc[mt][nt][r] + qb[nt]) * scl);
        }
    }
    __syncthreads();

    // ---- phase 3: per-(window,head) softmax; wave w -> window rep*4+w ----
#pragma unroll
    for (int rep = 0; rep < 2; ++rep) {
      const int win  = rep*4 + w;
      const int widx = wbase + win;
      const int wz = widx >> 10, wy = (widx >> 5) & 31, wx = widx & 31;
      const int hh = l >> 3, qi = l & 7;
      const int tq = win*8 + qi;
      float qr[8];
      {
        const short8 qv = *(const short8*)&qL[tq*72 + hh*8];
#pragma unroll
        for (int d = 0; d < 8; ++d) qr[d] = bf2f((u16)qv[d]);
      }
      float sc8[8];
#pragma unroll
      for (int kk = 0; kk < 8; ++kk) {
        const short8 kv = *(const short8*)&kL[(win*8 + kk)*72 + hh*8];
        float a = 0.f;
#pragma unroll
        for (int d = 0; d < 8; ++d) a += qr[d] * bf2f((u16)kv[d]);
        sc8[kk] = a;
      }
      {
        const int rel = 3 * (((hh>>1)&1) - ((qi>>1)&1) + 1)
                      +     (((hh>>2)&1) - ((qi>>2)&1) + 1)
                      +     (( hh    &1) - ( qi    &1) + 1);
#pragma unroll
        for (int kk = 0; kk < 8; ++kk) sc8[kk] += ld<F32>(rpb, rel*8 + kk);
      }
      {
        int cnts[8];
#pragma unroll
        for (int p = 0; p < 8; ++p) {
          const int sd = 2*wz + ((p>>2)&1);
          const int sh = 2*wy + ((p>>1)&1);
          const int sw = 2*wx + (p&1);
          const int rd = sd >= 62 ? sd - 61 : 0;
          const int rh = sh >= 62 ? sh - 61 : 0;
          const int rw = sw >= 62 ? sw - 61 : 0;
          cnts[p] = rd*9 + rh*3 + rw;
        }
#pragma unroll
        for (int kk = 0; kk < 8; ++kk)
          if (cnts[kk] != cnts[qi]) sc8[kk] -= 100.f;
      }
      float mx = sc8[0];
#pragma unroll
      for (int kk = 1; kk < 8; ++kk) mx = fmaxf(mx, sc8[kk]);
      float pr[8], lsum = 0.f;
#pragma unroll
      for (int kk = 0; kk < 8; ++kk) { pr[kk] = expf(sc8[kk] - mx); lsum += pr[kk]; }
      const float inv = 1.f / lsum;
      float o[8];
#pragma unroll
      for (int d = 0; d < 8; ++d) o[d] = 0.f;
#pragma unroll
      for (int kk = 0; kk < 8; ++kk) {
        const short8 vv = *(const short8*)&vL[(win*8 + kk)*72 + hh*8];
#pragma unroll
        for (int d = 0; d < 8; ++d) o[d] += pr[kk] * bf2f((u16)vv[d]);
      }
      short8 ov;
#pragma unroll
      for (int d = 0; d < 8; ++d) ov[d] = (short)f2bf(o[d] * inv);
      *(short8*)&aL[tq*72 + hh*8] = ov;      // O reuses aL (fenced by barriers)
    }
    __syncthreads();

    // ---- phase 4: proj MFMA + scattered residual epilogue ----
    f32x4 acc2[4];
#pragma unroll
    for (int mt = 0; mt < 4; ++mt) acc2[mt] = (f32x4){0.f,0.f,0.f,0.f};
#pragma unroll
    for (int kt = 0; kt < 2; ++kt)
#pragma unroll
      for (int mt = 0; mt < 4; ++mt) {
        const short8 aF = *(const short8*)&aL[(mt*16 + col)*72 + kt*32 + quad*8];
        acc2[mt] = __builtin_amdgcn_mfma_f32_16x16x32_bf16(
            aF, bp[kt], acc2[mt], 0, 0, 0);
      }
#pragma unroll
    for (int mt = 0; mt < 4; ++mt)
#pragma unroll
      for (int r = 0; r < 4; ++r) {
        const int tok  = mt*16 + quad*4 + r;
        const int widx = wbase + (tok >> 3);
        const int s    = tok & 7;
        const int wz = widx >> 10, wy = (widx >> 5) & 31, wx = widx & 31;
        const int fd = (2*wz + ((wy>>3)&1) + 1) & 63;
        const int Hb = 8*(wy&7) + 4*(wx>>4) + (wy>>4);
        const int Wb = 4*(wx&15);
        const int i = (s>>2)&1, j = (s>>1)&1, k = s&1;
        const int fh = (Hb + 2*j + 1) & 63;
        const int fw = (Wb + 2*i + k + 1) & 63;
        const int off = (((b<<18) + ((fd<<12)|(fh<<6)|fw)) << 6) + w*16 + col;
        out[off] = ld<F32>(x, off) + acc2[mt][r] + pb;
      }
    __syncthreads();   // protect aL/q/k/v before next chunk's phase 1
  }
}

__global__ __launch_bounds__(256)
void attn_kernel(const void* __restrict__ x,
                 const void* __restrict__ n1g, const void* __restrict__ n1b,
                 const void* __restrict__ qkvw, const void* __restrict__ qkvb,
                 const void* __restrict__ rpb,
                 const void* __restrict__ projw, const void* __restrict__ projb,
                 const int* __restrict__ flag, float* __restrict__ out)
{
  __shared__ __align__(16) u16 aL[64*72];   // 9.2 KB  LN'd A / attention O
  __shared__ __align__(16) u16 qL[64*72];   // 9.2 KB
  __shared__ __align__(16) u16 kL[64*72];   // 9.2 KB
  __shared__ __align__(16) u16 vL[64*72];   // 9.2 KB   (36.9 KB total)
  if (*flag)
    attn_body<true >(x, n1g, n1b, qkvw, qkvb, rpb, projw, projb, out, aL, qL, kL, vL);
  else
    attn_body<false>(x, n1g, n1b, qkvw, qkvb, rpb, projw, projb, out, aL, qL, kL, vL);
}

// ---------------------------------------------------------------------------
// Kernel 2 (MFMA): LN2 + MLP(64->256 GELU ->64) + residual, in-place.
// Unchanged from previous round (passing).
// ---------------------------------------------------------------------------
template<bool F32>
__device__ __forceinline__ void mlp_body(
    float* __restrict__ io,
    const void* __restrict__ n2g, const void* __restrict__ n2b,
    const void* __restrict__ mw1, const void* __restrict__ mb1,
    const void* __restrict__ mw2, const void* __restrict__ mb2,
    u16* __restrict__ aL, u16* __restrict__ hL)
{
  const int tid  = threadIdx.x;
  const int w    = tid >> 6, l = tid & 63;
  const int quad = l >> 4,  col = l & 15;

  const float g2 = ld<F32>(n2g, l), be2 = ld<F32>(n2b, l);

  short8 b1f[2][4];                  // [kt][nt], phase1 cols w*64+nt*16+col
#pragma unroll
  for (int kt = 0; kt < 2; ++kt)
#pragma unroll
    for (int nt = 0; nt < 4; ++nt) {
      short8 f;
#pragma unroll
      for (int j = 0; j < 8; ++j) {
        const int k = kt*32 + quad*8 + j;
        const int n = w*64 + nt*16 + col;
        f[j] = (short)f2bf(ld<F32>(mw1, k*256 + n));
      }
      b1f[kt][nt] = f;
    }
  short8 b2f[8];                     // [kt], phase2 col w*16+col
#pragma unroll
  for (int kt = 0; kt < 8; ++kt) {
    short8 f;
#pragma unroll
    for (int j = 0; j < 8; ++j) {
      const int k = kt*32 + quad*8 + j;
      f[j] = (short)f2bf(ld<F32>(mw2, k*64 + w*16 + col));
    }
    b2f[kt] = f;
  }
  float b1v[4];
#pragma unroll
  for (int nt = 0; nt < 4; ++nt) b1v[nt] = ld<F32>(mb1, w*64 + nt*16 + col);
  const float b2v = ld<F32>(mb2, w*16 + col);

  for (int chunk = blockIdx.x; chunk < 8192; chunk += gridDim.x) {
    const int T0 = chunk * 64;

#pragma unroll 4
    for (int t = 0; t < 16; ++t) {
      const int tok = T0 + w*16 + t;
      const float v = io[tok*64 + l];
      float s1 = v, sq = v * v;
#pragma unroll
      for (int m = 1; m < 64; m <<= 1) {
        s1 += __shfl_xor(s1, m);
        sq += __shfl_xor(sq, m);
      }
      const float mu  = s1 * 0.015625f;
      const float var = sq * 0.015625f - mu * mu;
      aL[(w*16 + t)*72 + l] = f2bf((v - mu) * rsqrtf(var + 1e-5f) * g2 + be2);
    }
    __syncthreads();

    f32x4 acc[4][4];
#pragma unroll
    for (int mt = 0; mt < 4; ++mt)
#pragma unroll
      for (int nt = 0; nt < 4; ++nt) acc[mt][nt] = (f32x4){0.f,0.f,0.f,0.f};
#pragma unroll
    for (int kt = 0; kt < 2; ++kt) {
      short8 aF[4];
#pragma unroll
      for (int mt = 0; mt < 4; ++mt)
        aF[mt] = *(const short8*)&aL[(mt*16 + col)*72 + kt*32 + quad*8];
#pragma unroll
      for (int mt = 0; mt < 4; ++mt)
#pragma unroll
        for (int nt = 0; nt < 4; ++nt)
          acc[mt][nt] = __builtin_amdgcn_mfma_f32_16x16x32_bf16(
              aF[mt], b1f[kt][nt], acc[mt][nt], 0, 0, 0);
    }

#pragma unroll
    for (int mt = 0; mt < 4; ++mt)
#pragma unroll
      for (int nt = 0; nt < 4; ++nt)
#pragma unroll
        for (int r = 0; r < 4; ++r) {
          const float h = acc[mt][nt][r] + b1v[nt];
          const float g = 0.5f * h * (1.f + erff(h * 0.70710678118654752f));
          hL[(mt*16 + quad*4 + r)*264 + w*64 + nt*16 + col] = f2bf(g);
        }
    __syncthreads();

    f32x4 acc2[4];
#pragma unroll
    for (int mt = 0; mt < 4; ++mt) acc2[mt] = (f32x4){0.f,0.f,0.f,0.f};
#pragma unroll
    for (int kt = 0; kt < 8; ++kt)
#pragma unroll
      for (int mt = 0; mt < 4; ++mt) {
        const short8 aF = *(const short8*)&hL[(mt*16 + col)*264 + kt*32 + quad*8];
        acc2[mt] = __builtin_amdgcn_mfma_f32_16x16x32_bf16(
            aF, b2f[kt], acc2[mt], 0, 0, 0);
      }

#pragma unroll
    for (int mt = 0; mt < 4; ++mt)
#pragma unroll
      for (int r = 0; r < 4; ++r) {
        const int row = mt*16 + quad*4 + r;
        const int idx = (T0 + row)*64 + w*16 + col;
        io[idx] = io[idx] + acc2[mt][r] + b2v;
      }
  }
}

__global__ __launch_bounds__(256)
void mlp_kernel(float* __restrict__ io,
                const void* __restrict__ n2g, const void* __restrict__ n2b,
                const void* __restrict__ mw1, const void* __restrict__ mb1,
                const void* __restrict__ mw2, const void* __restrict__ mb2,
                const int* __restrict__ flag)
{
  __shared__ __align__(16) u16 aL[64 * 72];    //  9.2 KB, LN'd tokens (bf16)
  __shared__ __align__(16) u16 hL[64 * 264];   // 33.8 KB, hidden (bf16)
  if (*flag)
    mlp_body<true >(io, n2g, n2b, mw1, mb1, mw2, mb2, aL, hL);
  else
    mlp_body<false>(io, n2g, n2b, mw1, mb1, mw2, mb2, aL, hL);
}

extern "C" void kernel_launch(void* const* d_in, const int* in_sizes, int n_in,
                              void* d_out, int out_size, void* d_ws, size_t ws_size,
                              hipStream_t stream) {
  const void* x     = d_in[0];
  const void* n1g   = d_in[1];
  const void* n1b   = d_in[2];
  const void* qkvw  = d_in[3];
  const void* qkvb  = d_in[4];
  const void* rpb   = d_in[5];
  const void* projw = d_in[6];
  const void* projb = d_in[7];
  const void* n2g   = d_in[8];
  const void* n2b   = d_in[9];
  const void* mw1   = d_in[10];
  const void* mb1   = d_in[11];
  const void* mw2   = d_in[12];
  const void* mb2   = d_in[13];
  float* out = (float*)d_out;
  int* flag  = (int*)d_ws;

  detect_kernel<<<dim3(1), dim3(64), 0, stream>>>(x, flag);
  attn_kernel<<<dim3(2048), dim3(256), 0, stream>>>(
      x, n1g, n1b, qkvw, qkvb, rpb, projw, projb, flag, out);
  mlp_kernel<<<dim3(2048), dim3(256), 0, stream>>>(
      out, n2g, n2b, mw1, mb1, mw2, mb2, flag);
}

// Round 2
// 548.711 us; speedup vs baseline: 1.5530x; 1.2398x over previous
//
#include <hip/hip_runtime.h>
#include <math.h>

typedef unsigned short u16;
typedef unsigned int u32;
typedef __attribute__((ext_vector_type(8))) short short8;   // 8 bf16 (4 VGPRs)
typedef __attribute__((ext_vector_type(4))) float f32x4;

__device__ __forceinline__ float bf2f(u16 u) {
  union { u32 i; float f; } v; v.i = ((u32)u) << 16; return v.f;
}
__device__ __forceinline__ u16 f2bf(float f) {
  union { float f; u32 i; } v; v.f = f;
  u32 i = v.i;
  i += 0x7fffu + ((i >> 16) & 1u);   // round-to-nearest-even
  return (u16)(i >> 16);
}

// dtype-polymorphic loads (F32: inputs are float32; else bf16 bits)
template<bool F32>
__device__ __forceinline__ float ld(const void* p, int i) {
  if (F32) return ((const float*)p)[i];
  return bf2f(((const u16*)p)[i]);
}

// ---------------------------------------------------------------------------
// Kernel 0: detect input dtype (fp32 vs bf16-packed).
// ---------------------------------------------------------------------------
__global__ __launch_bounds__(64)
void detect_kernel(const void* __restrict__ xv, int* __restrict__ flag) {
  const u32* xw = (const u32*)xv;
  const int t = threadIdx.x;
  int bad = 0;
  for (int i = t; i < 1024; i += 64) {
    const int e = (int)((xw[i] >> 7) & 0xFF);
    if (e < 90 || e > 150) bad++;
  }
#pragma unroll
  for (int m = 1; m < 64; m <<= 1) bad += __shfl_xor(bad, m);
  if (t == 0) *flag = (bad > 256) ? 1 : 0;
}

// ---------------------------------------------------------------------------
// Kernel 1: LN1 + shifted-window attention + proj + residual.
// Block = 256 thr (4 waves), chunk = 4 windows = 32 tokens, 16384 chunks,
// persistent grid of 2048 blocks (weight fragments preloaded in registers).
// Wave w owns window w of its chunk end-to-end in phase 3.
// Occupancy-tuned: LDS 18.4 KB, __launch_bounds__(256,4) -> VGPR<=128.
// Barriers: 3/chunk (O written to qL = per-wave rows, trailing bar removed).
// ---------------------------------------------------------------------------
template<bool F32>
__device__ __forceinline__ void attn_body(
    const void* __restrict__ x,
    const void* __restrict__ n1g, const void* __restrict__ n1b,
    const void* __restrict__ qkvw, const void* __restrict__ qkvb,
    const void* __restrict__ rpb,
    const void* __restrict__ projw, const void* __restrict__ projb,
    float* __restrict__ out,
    u16* __restrict__ aL, u16* __restrict__ qL,
    u16* __restrict__ kL, u16* __restrict__ vL)
{
  const int tid  = threadIdx.x;
  const int w    = tid >> 6, l = tid & 63;
  const int quad = l >> 4,  col = l & 15;

  const float g1 = ld<F32>(n1g, l), be1 = ld<F32>(n1b, l);

  // ---- preload B-fragments into registers (once per block) ----
  short8 bq[3][2];                 // qkv cols w*48 + nt*16 + col, [nt][kt]
#pragma unroll
  for (int nt = 0; nt < 3; ++nt)
#pragma unroll
    for (int kt = 0; kt < 2; ++kt) {
      short8 f;
#pragma unroll
      for (int j = 0; j < 8; ++j) {
        const int k = kt*32 + quad*8 + j;
        f[j] = (short)f2bf(ld<F32>(qkvw, k*192 + w*48 + nt*16 + col));
      }
      bq[nt][kt] = f;
    }
  float qb[3];
#pragma unroll
  for (int nt = 0; nt < 3; ++nt) qb[nt] = ld<F32>(qkvb, w*48 + nt*16 + col);
  short8 bp[2];                    // proj cols w*16 + col, [kt]
#pragma unroll
  for (int kt = 0; kt < 2; ++kt) {
    short8 f;
#pragma unroll
    for (int j = 0; j < 8; ++j) {
      const int k = kt*32 + quad*8 + j;
      f[j] = (short)f2bf(ld<F32>(projw, k*64 + w*16 + col));
    }
    bp[kt] = f;
  }
  const float pb = ld<F32>(projb, w*16 + col);

  for (int chunk = blockIdx.x; chunk < 16384; chunk += gridDim.x) {
    const int b     = chunk >> 13;
    const int wbase = (chunk & 8191) << 2;   // first of 4 windows

    // this wave's window (phases 1 & 3)
    const int widx0 = wbase + w;
    const int wz0 = widx0 >> 10, wy0 = (widx0 >> 5) & 31, wx0 = widx0 & 31;

    // ---- phase 1: LN1 + shifted gather (lane = channel), 8 tokens/wave ----
#pragma unroll
    for (int t = 0; t < 8; ++t) {
      const int od = (2*wz0 + ((t>>2)&1) + 1) & 63;
      const int oh = (2*wy0 + ((t>>1)&1) + 1) & 63;
      const int ow = (2*wx0 + ( t    &1) + 1) & 63;
      const float v = ld<F32>(x, (((b<<18) + ((od<<12)|(oh<<6)|ow)) << 6) + l);
      float s1 = v, sq = v * v;
#pragma unroll
      for (int m = 1; m < 64; m <<= 1) {
        s1 += __shfl_xor(s1, m);
        sq += __shfl_xor(sq, m);
      }
      const float mu  = s1 * 0.015625f;
      const float var = sq * 0.015625f - mu * mu;
      aL[(w*8 + t)*72 + l] = f2bf((v - mu) * rsqrtf(var + 1e-5f) * g1 + be1);
    }
    __syncthreads();

    // ---- phase 2: QKV MFMA, A[32x64] @ wave's 64x48 slab -> q/k/v LDS ----
    f32x4 acc[2][3];
#pragma unroll
    for (int mt = 0; mt < 2; ++mt)
#pragma unroll
      for (int nt = 0; nt < 3; ++nt) acc[mt][nt] = (f32x4){0.f,0.f,0.f,0.f};
#pragma unroll
    for (int kt = 0; kt < 2; ++kt) {
      short8 aF[2];
#pragma unroll
      for (int mt = 0; mt < 2; ++mt)
        aF[mt] = *(const short8*)&aL[(mt*16 + col)*72 + kt*32 + quad*8];
#pragma unroll
      for (int mt = 0; mt < 2; ++mt)
#pragma unroll
        for (int nt = 0; nt < 3; ++nt)
          acc[mt][nt] = __builtin_amdgcn_mfma_f32_16x16x32_bf16(
              aF[mt], bq[nt][kt], acc[mt][nt], 0, 0, 0);
    }
#pragma unroll
    for (int nt = 0; nt < 3; ++nt) {
      const int nb  = w*48 + nt*16;                 // global qkv col base
      u16* dst      = (nb < 64) ? qL : (nb < 128) ? kL : vL;
      const int chb = (nb & 63) + col;
      const float scl = (nb < 64) ? 0.35355339059327373f : 1.0f;
#pragma unroll
      for (int mt = 0; mt < 2; ++mt)
#pragma unroll
        for (int r = 0; r < 4; ++r) {
          const int tokr = mt*16 + quad*4 + r;
          dst[tokr*72 + chb] = f2bf((acc[mt][nt][r] + qb[nt]) * scl);
        }
    }
    __syncthreads();

    // ---- phase 3: softmax for window w (lane = (head, query)) ----
    {
      const int hh = l >> 3, qi = l & 7;
      const int tq = w*8 + qi;
      float qr[8];
      {
        const short8 qv = *(const short8*)&qL[tq*72 + hh*8];
#pragma unroll
        for (int d = 0; d < 8; ++d) qr[d] = bf2f((u16)qv[d]);
      }
      float sc8[8];
#pragma unroll
      for (int kk = 0; kk < 8; ++kk) {
        const short8 kv = *(const short8*)&kL[(w*8 + kk)*72 + hh*8];
        float a = 0.f;
#pragma unroll
        for (int d = 0; d < 8; ++d) a += qr[d] * bf2f((u16)kv[d]);
        sc8[kk] = a;
      }
      {
        const int rel = 3 * (((hh>>1)&1) - ((qi>>1)&1) + 1)
                      +     (((hh>>2)&1) - ((qi>>2)&1) + 1)
                      +     (( hh    &1) - ( qi    &1) + 1);
#pragma unroll
        for (int kk = 0; kk < 8; ++kk) sc8[kk] += ld<F32>(rpb, rel*8 + kk);
      }
      {
        int cnts[8];
#pragma unroll
        for (int p = 0; p < 8; ++p) {
          const int sd = 2*wz0 + ((p>>2)&1);
          const int sh = 2*wy0 + ((p>>1)&1);
          const int sw = 2*wx0 + (p&1);
          const int rd = sd >= 62 ? sd - 61 : 0;
          const int rh = sh >= 62 ? sh - 61 : 0;
          const int rw = sw >= 62 ? sw - 61 : 0;
          cnts[p] = rd*9 + rh*3 + rw;
        }
#pragma unroll
        for (int kk = 0; kk < 8; ++kk)
          if (cnts[kk] != cnts[qi]) sc8[kk] -= 100.f;
      }
      float mx = sc8[0];
#pragma unroll
      for (int kk = 1; kk < 8; ++kk) mx = fmaxf(mx, sc8[kk]);
      float pr[8], lsum = 0.f;
#pragma unroll
      for (int kk = 0; kk < 8; ++kk) { pr[kk] = __expf(sc8[kk] - mx); lsum += pr[kk]; }
      const float inv = __builtin_amdgcn_rcpf(lsum);
      float o[8];
#pragma unroll
      for (int d = 0; d < 8; ++d) o[d] = 0.f;
#pragma unroll
      for (int kk = 0; kk < 8; ++kk) {
        const short8 vv = *(const short8*)&vL[(w*8 + kk)*72 + hh*8];
#pragma unroll
        for (int d = 0; d < 8; ++d) o[d] += pr[kk] * bf2f((u16)vv[d]);
      }
      short8 ov;
#pragma unroll
      for (int d = 0; d < 8; ++d) ov[d] = (short)f2bf(o[d] * inv);
      // O -> qL (this wave's own rows; q-reads above complete in-order)
      *(short8*)&qL[tq*72 + hh*8] = ov;
    }
    __syncthreads();

    // ---- phase 4: proj MFMA (A = O from qL) + scattered residual ----
    f32x4 acc2[2];
#pragma unroll
    for (int mt = 0; mt < 2; ++mt) acc2[mt] = (f32x4){0.f,0.f,0.f,0.f};
#pragma unroll
    for (int kt = 0; kt < 2; ++kt)
#pragma unroll
      for (int mt = 0; mt < 2; ++mt) {
        const short8 aF = *(const short8*)&qL[(mt*16 + col)*72 + kt*32 + quad*8];
        acc2[mt] = __builtin_amdgcn_mfma_f32_16x16x32_bf16(
            aF, bp[kt], acc2[mt], 0, 0, 0);
      }
#pragma unroll
    for (int mt = 0; mt < 2; ++mt)
#pragma unroll
      for (int r = 0; r < 4; ++r) {
        const int tok  = mt*16 + quad*4 + r;
        const int widx = wbase + (tok >> 3);
        const int s    = tok & 7;
        const int wz = widx >> 10, wy = (widx >> 5) & 31, wx = widx & 31;
        const int fd = (2*wz + ((wy>>3)&1) + 1) & 63;
        const int Hb = 8*(wy&7) + 4*(wx>>4) + (wy>>4);
        const int Wb = 4*(wx&15);
        const int i = (s>>2)&1, j = (s>>1)&1, k = s&1;
        const int fh = (Hb + 2*j + 1) & 63;
        const int fw = (Wb + 2*i + k + 1) & 63;
        const int off = (((b<<18) + ((fd<<12)|(fh<<6)|fw)) << 6) + w*16 + col;
        out[off] = ld<F32>(x, off) + acc2[mt][r] + pb;
      }
    // no trailing barrier: next LN writes aL, whose phase-2 readers all
    // passed the post-LN barrier; qL/kL/vL rewrites are fenced by it too.
    __syncthreads();   // (kept minimal: fences phase-4 qL reads vs next phase-2 writes)
  }
}

__global__ __launch_bounds__(256, 4)
void attn_kernel(const void* __restrict__ x,
                 const void* __restrict__ n1g, const void* __restrict__ n1b,
                 const void* __restrict__ qkvw, const void* __restrict__ qkvb,
                 const void* __restrict__ rpb,
                 const void* __restrict__ projw, const void* __restrict__ projb,
                 const int* __restrict__ flag, float* __restrict__ out)
{
  __shared__ __align__(16) u16 aL[32*72];   // 4.6 KB  LN'd A
  __shared__ __align__(16) u16 qL[32*72];   // 4.6 KB  q, then O
  __shared__ __align__(16) u16 kL[32*72];   // 4.6 KB
  __shared__ __align__(16) u16 vL[32*72];   // 4.6 KB   (18.4 KB total)
  if (*flag)
    attn_body<true >(x, n1g, n1b, qkvw, qkvb, rpb, projw, projb, out, aL, qL, kL, vL);
  else
    attn_body<false>(x, n1g, n1b, qkvw, qkvb, rpb, projw, projb, out, aL, qL, kL, vL);
}

// ---------------------------------------------------------------------------
// Kernel 2: LN2 + MLP(64->256 GELU ->64) + residual, in-place.
// Chunk = 32 tokens (16384 chunks), block 256 thr, persistent grid 2048.
// LDS 21.5 KB, __launch_bounds__(256,4). GELU: tanh form via __expf
// (error ~1e-3 in h, attenuated ~30x through W2; absmax impact negligible).
// ---------------------------------------------------------------------------
template<bool F32>
__device__ __forceinline__ void mlp_body(
    float* __restrict__ io,
    const void* __restrict__ n2g, const void* __restrict__ n2b,
    const void* __restrict__ mw1, const void* __restrict__ mb1,
    const void* __restrict__ mw2, const void* __restrict__ mb2,
    u16* __restrict__ aL, u16* __restrict__ hL)
{
  const int tid  = threadIdx.x;
  const int w    = tid >> 6, l = tid & 63;
  const int quad = l >> 4,  col = l & 15;

  const float g2 = ld<F32>(n2g, l), be2 = ld<F32>(n2b, l);

  short8 b1f[2][4];                  // [kt][nt], phase1 cols w*64+nt*16+col
#pragma unroll
  for (int kt = 0; kt < 2; ++kt)
#pragma unroll
    for (int nt = 0; nt < 4; ++nt) {
      short8 f;
#pragma unroll
      for (int j = 0; j < 8; ++j) {
        const int k = kt*32 + quad*8 + j;
        const int n = w*64 + nt*16 + col;
        f[j] = (short)f2bf(ld<F32>(mw1, k*256 + n));
      }
      b1f[kt][nt] = f;
    }
  short8 b2f[8];                     // [kt], phase2 col w*16+col
#pragma unroll
  for (int kt = 0; kt < 8; ++kt) {
    short8 f;
#pragma unroll
    for (int j = 0; j < 8; ++j) {
      const int k = kt*32 + quad*8 + j;
      f[j] = (short)f2bf(ld<F32>(mw2, k*64 + w*16 + col));
    }
    b2f[kt] = f;
  }
  float b1v[4];
#pragma unroll
  for (int nt = 0; nt < 4; ++nt) b1v[nt] = ld<F32>(mb1, w*64 + nt*16 + col);
  const float b2v = ld<F32>(mb2, w*16 + col);

  for (int chunk = blockIdx.x; chunk < 16384; chunk += gridDim.x) {
    const int T0 = chunk * 32;

    // ---- LN2: wave w handles 8 tokens (lane = channel) ----
#pragma unroll
    for (int t = 0; t < 8; ++t) {
      const int tok = T0 + w*8 + t;
      const float v = io[tok*64 + l];
      float s1 = v, sq = v * v;
#pragma unroll
      for (int m = 1; m < 64; m <<= 1) {
        s1 += __shfl_xor(s1, m);
        sq += __shfl_xor(sq, m);
      }
      const float mu  = s1 * 0.015625f;
      const float var = sq * 0.015625f - mu * mu;
      aL[(w*8 + t)*72 + l] = f2bf((v - mu) * rsqrtf(var + 1e-5f) * g2 + be2);
    }
    __syncthreads();

    // ---- phase 1: 32x64 @ 64x256 -> wave's 32x64 slab ----
    f32x4 acc[2][4];
#pragma unroll
    for (int mt = 0; mt < 2; ++mt)
#pragma unroll
      for (int nt = 0; nt < 4; ++nt) acc[mt][nt] = (f32x4){0.f,0.f,0.f,0.f};
#pragma unroll
    for (int kt = 0; kt < 2; ++kt) {
      short8 aF[2];
#pragma unroll
      for (int mt = 0; mt < 2; ++mt)
        aF[mt] = *(const short8*)&aL[(mt*16 + col)*72 + kt*32 + quad*8];
#pragma unroll
      for (int mt = 0; mt < 2; ++mt)
#pragma unroll
        for (int nt = 0; nt < 4; ++nt)
          acc[mt][nt] = __builtin_amdgcn_mfma_f32_16x16x32_bf16(
              aF[mt], b1f[kt][nt], acc[mt][nt], 0, 0, 0);
    }

    // ---- bias + tanh-GELU + pack bf16 -> H in LDS ----
#pragma unroll
    for (int mt = 0; mt < 2; ++mt)
#pragma unroll
      for (int nt = 0; nt < 4; ++nt)
#pragma unroll
        for (int r = 0; r < 4; ++r) {
          const float h = acc[mt][nt][r] + b1v[nt];
          // gelu(h) = h * e/(e+1), e = exp(2*0.79788456*(h+0.044715h^3))
          const float u = h * (1.5957691216f + 0.0713548162f * (h * h));
          const float e = __expf(u);
          const float g = h - h * __builtin_amdgcn_rcpf(e + 1.f);
          hL[(mt*16 + quad*4 + r)*264 + w*64 + nt*16 + col] = f2bf(g);
        }
    __syncthreads();

    // ---- phase 2: 32x256 @ 256x64 -> wave's 32x16 slab ----
    f32x4 acc2[2];
#pragma unroll
    for (int mt = 0; mt < 2; ++mt) acc2[mt] = (f32x4){0.f,0.f,0.f,0.f};
#pragma unroll
    for (int kt = 0; kt < 8; ++kt)
#pragma unroll
      for (int mt = 0; mt < 2; ++mt) {
        const short8 aF = *(const short8*)&hL[(mt*16 + col)*264 + kt*32 + quad*8];
        acc2[mt] = __builtin_amdgcn_mfma_f32_16x16x32_bf16(
            aF, b2f[kt], acc2[mt], 0, 0, 0);
      }

    // ---- residual read-modify-write (fp32, L2-hot) ----
#pragma unroll
    for (int mt = 0; mt < 2; ++mt)
#pragma unroll
      for (int r = 0; r < 4; ++r) {
        const int row = mt*16 + quad*4 + r;
        const int idx = (T0 + row)*64 + w*16 + col;
        io[idx] = io[idx] + acc2[mt][r] + b2v;
      }
    // aL rewrite next chunk is fenced by the post-hL barrier (all phase-1
    // reads of aL complete before any wave passes it).
  }
}

__global__ __launch_bounds__(256, 4)
void mlp_kernel(float* __restrict__ io,
                const void* __restrict__ n2g, const void* __restrict__ n2b,
                const void* __restrict__ mw1, const void* __restrict__ mb1,
                const void* __restrict__ mw2, const void* __restrict__ mb2,
                const int* __restrict__ flag)
{
  __shared__ __align__(16) u16 aL[32 * 72];    //  4.6 KB, LN'd tokens (bf16)
  __shared__ __align__(16) u16 hL[32 * 264];   // 16.9 KB, hidden (bf16)
  if (*flag)
    mlp_body<true >(io, n2g, n2b, mw1, mb1, mw2, mb2, aL, hL);
  else
    mlp_body<false>(io, n2g, n2b, mw1, mb1, mw2, mb2, aL, hL);
}

extern "C" void kernel_launch(void* const* d_in, const int* in_sizes, int n_in,
                              void* d_out, int out_size, void* d_ws, size_t ws_size,
                              hipStream_t stream) {
  const void* x     = d_in[0];
  const void* n1g   = d_in[1];
  const void* n1b   = d_in[2];
  const void* qkvw  = d_in[3];
  const void* qkvb  = d_in[4];
  const void* rpb   = d_in[5];
  const void* projw = d_in[6];
  const void* projb = d_in[7];
  const void* n2g   = d_in[8];
  const void* n2b   = d_in[9];
  const void* mw1   = d_in[10];
  const void* mb1   = d_in[11];
  const void* mw2   = d_in[12];
  const void* mb2   = d_in[13];
  float* out = (float*)d_out;
  int* flag  = (int*)d_ws;

  detect_kernel<<<dim3(1), dim3(64), 0, stream>>>(x, flag);
  attn_kernel<<<dim3(2048), dim3(256), 0, stream>>>(
      x, n1g, n1b, qkvw, qkvb, rpb, projw, projb, flag, out);
  mlp_kernel<<<dim3(2048), dim3(256), 0, stream>>>(
      out, n2g, n2b, mw1, mb1, mw2, mb2, flag);
}